// Round 14
// baseline (88.856 us; speedup 1.0000x reference)
//
#include <hip/hip_runtime.h>
#include <hip/hip_bf16.h>

#define DNBR   16
#define INDIM  128
#define OUTDIM 64

typedef __attribute__((ext_vector_type(8))) short bf16x8;
typedef __attribute__((ext_vector_type(4))) float f32x4;
typedef __attribute__((ext_vector_type(4))) unsigned u32x4;

union BF8 { bf16x8 v; u32x4 u; };

__device__ __forceinline__ unsigned cvt_pk_bf16(float lo, float hi) {
    unsigned r;
    asm("v_cvt_pk_bf16_f32 %0, %1, %2" : "=v"(r) : "v"(lo), "v"(hi));
    return r;
}

// ---------------- Phase 1: z = h @ W_fc^T via bf16 MFMA, + s_src/s_dst -------
__global__ __launch_bounds__(256) void fc_mfma(
    const float* __restrict__ h, const float* __restrict__ W_fc,
    const float* __restrict__ W_attn, __hip_bfloat16* __restrict__ zb,
    float* __restrict__ s_src, float* __restrict__ s_dst, int n)
{
    __shared__ unsigned wl[4096];   // 16 KB: slot(ct,kk,lane) -> 4 u32 (8 bf16)

    const int tid = threadIdx.x;
    #pragma unroll
    for (int s4 = 0; s4 < 4; ++s4) {
        const int slot = tid + 256 * s4;      // 0..1023
        const int lane_s = slot & 63;
        const int ckk  = slot >> 6;           // ct*4+kk
        const int ct_s = ckk >> 2, kk_s = ckk & 3;
        const int lm_s = lane_s & 15, lg_s = lane_s >> 4;
        const float* wr = W_fc + (size_t)(ct_s * 16 + lm_s) * INDIM + kk_s * 32 + lg_s * 8;
        const float4 w0 = *reinterpret_cast<const float4*>(wr);
        const float4 w1 = *reinterpret_cast<const float4*>(wr + 4);
        wl[slot * 4 + 0] = cvt_pk_bf16(w0.x, w0.y);
        wl[slot * 4 + 1] = cvt_pk_bf16(w0.z, w0.w);
        wl[slot * 4 + 2] = cvt_pk_bf16(w1.x, w1.y);
        wl[slot * 4 + 3] = cvt_pk_bf16(w1.z, w1.w);
    }
    __syncthreads();

    const int lane  = threadIdx.x & 63;
    const int wid   = threadIdx.x >> 6;
    const int node0 = blockIdx.x * 64 + wid * 16;
    if (node0 >= n) return;
    const int lm = lane & 15;
    const int lg = lane >> 4;

    bf16x8 bfrag[4][4];
    #pragma unroll
    for (int ct = 0; ct < 4; ++ct)
        #pragma unroll
        for (int kk = 0; kk < 4; ++kk) {
            BF8 u;
            u.u = *reinterpret_cast<const u32x4*>(&wl[(size_t)((ct * 4 + kk) * 64 + lane) * 4]);
            bfrag[ct][kk] = u.v;
        }

    const int arow = (node0 + lm < n) ? (node0 + lm) : (n - 1);
    const float* hr = h + (size_t)arow * INDIM;
    bf16x8 af[4];
    #pragma unroll
    for (int kk = 0; kk < 4; ++kk) {
        const float4 a0 = *reinterpret_cast<const float4*>(hr + kk * 32 + lg * 8);
        const float4 a1 = *reinterpret_cast<const float4*>(hr + kk * 32 + lg * 8 + 4);
        BF8 u;
        u.u[0] = cvt_pk_bf16(a0.x, a0.y);
        u.u[1] = cvt_pk_bf16(a0.z, a0.w);
        u.u[2] = cvt_pk_bf16(a1.x, a1.y);
        u.u[3] = cvt_pk_bf16(a1.z, a1.w);
        af[kk] = u.v;
    }

    f32x4 acc[4];
    #pragma unroll
    for (int ct = 0; ct < 4; ++ct) acc[ct] = (f32x4){0.f, 0.f, 0.f, 0.f};
    #pragma unroll
    for (int kk = 0; kk < 4; ++kk)
        #pragma unroll
        for (int ct = 0; ct < 4; ++ct)
            acc[ct] = __builtin_amdgcn_mfma_f32_16x16x32_bf16(af[kk], bfrag[ct][kk], acc[ct], 0, 0, 0);

    float ps[4] = {0.f, 0.f, 0.f, 0.f};
    float pd[4] = {0.f, 0.f, 0.f, 0.f};
    unsigned short* zbs = reinterpret_cast<unsigned short*>(zb);
    #pragma unroll
    for (int ct = 0; ct < 4; ++ct) {
        const float as = W_attn[ct * 16 + lm];
        const float ad = W_attn[OUTDIM + ct * 16 + lm];
        #pragma unroll
        for (int r = 0; r < 4; ++r) {
            const float v = acc[ct][r];                 // C[(lg*4+r)][ct*16+lm]
            const int grow = node0 + lg * 4 + r;
            if (grow < n)
                zbs[(size_t)grow * OUTDIM + ct * 16 + lm] =
                    (unsigned short)(cvt_pk_bf16(v, v) & 0xFFFFu);
            ps[r] = fmaf(v, as, ps[r]);
            pd[r] = fmaf(v, ad, pd[r]);
        }
    }
    #pragma unroll
    for (int off = 1; off < 16; off <<= 1) {
        #pragma unroll
        for (int r = 0; r < 4; ++r) {
            ps[r] += __shfl_xor(ps[r], off, 64);
            pd[r] += __shfl_xor(pd[r], off, 64);
        }
    }
    if (lm == 0) {
        #pragma unroll
        for (int r = 0; r < 4; ++r) {
            const int grow = node0 + lg * 4 + r;
            if (grow < n) { s_src[grow] = ps[r]; s_dst[grow] = pd[r]; }
        }
    }
}

// ---------------- exact entmax15 over 16 values (weights = y^2) ---------------
__device__ __forceinline__ void entmax15_weights(float x[DNBR], float wout[DNBR]) {
    float mx = x[0];
    #pragma unroll
    for (int j = 1; j < DNBR; ++j) mx = fmaxf(mx, x[j]);
    #pragma unroll
    for (int j = 0; j < DNBR; ++j) x[j] -= mx;

    float xs[DNBR];
    #pragma unroll
    for (int j = 0; j < DNBR; ++j) xs[j] = x[j];
    #pragma unroll
    for (int k = 2; k <= DNBR; k <<= 1) {
        #pragma unroll
        for (int s = k >> 1; s >= 1; s >>= 1) {
            #pragma unroll
            for (int i = 0; i < DNBR; ++i) {
                int l = i ^ s;
                if (l > i) {
                    const bool up = ((i & k) == 0);
                    float a = xs[i], b = xs[l];
                    float hi = fmaxf(a, b), lo = fminf(a, b);
                    xs[i] = up ? hi : lo;
                    xs[l] = up ? lo : hi;
                }
            }
        }
    }

    float taus[DNBR];
    float cs = 0.f, css = 0.f;
    int supp = 0;
    #pragma unroll
    for (int k = 0; k < DNBR; ++k) {
        cs  += xs[k];
        css += xs[k] * xs[k];
        const float kk = (float)(k + 1);
        const float mean   = cs  / kk;
        const float meansq = css / kk;
        const float ssv    = kk * (meansq - mean * mean);
        const float delta  = (1.f - ssv) / kk;
        const float sq     = (delta > 0.f) ? sqrtf(delta) : 0.f;
        taus[k] = mean - sq;
        supp += (taus[k] <= xs[k]) ? 1 : 0;
    }
    float tau_star = taus[0];
    #pragma unroll
    for (int k = 1; k < DNBR; ++k)
        tau_star = (supp - 1 == k) ? taus[k] : tau_star;

    #pragma unroll
    for (int j = 0; j < DNBR; ++j) {
        const float y = fmaxf(x[j] - tau_star, 0.f);
        wout[j] = y * y;
    }
}

// ---------------- Phase 2: serial entmax + COMPACT nonzero pairs -------------
// One thread per node. Writes cnt[node] and up to 16 (w, idx) 8B pairs.
// Runtime index c only appears in the global store address (no scratch).
__global__ __launch_bounds__(256) void alpha_kernel(
    const int* __restrict__ nbr, const float* __restrict__ wbias,
    const float* __restrict__ s_src, const float* __restrict__ s_dst,
    float2* __restrict__ alpha_c, int* __restrict__ cnt_arr, int n)
{
    const int node = blockIdx.x * 256 + threadIdx.x;
    if (node >= n) return;

    const int4*   nrow = reinterpret_cast<const int4*>(nbr + (size_t)node * DNBR);
    const float4* wrow = reinterpret_cast<const float4*>(wbias + (size_t)node * DNBR);
    const float sd = s_dst[node];

    int   nbs[DNBR];
    float x[DNBR];
    #pragma unroll
    for (int q = 0; q < 4; ++q) {
        const int4 v   = nrow[q];
        const float4 t = wrow[q];
        const int   nb4[4] = {v.x, v.y, v.z, v.w};
        const float w4[4]  = {t.x, t.y, t.z, t.w};
        #pragma unroll
        for (int j = 0; j < 4; ++j) {
            nbs[q * 4 + j] = nb4[j];
            float e = s_src[nb4[j]] + sd;          // static j select (unrolled)
            e = (e >= 0.f) ? e : 0.01f * e;
            x[q * 4 + j] = 0.5f * (e + w4[j]);
        }
    }

    float wts[DNBR];
    entmax15_weights(x, wts);

    float2* prow = alpha_c + (size_t)node * DNBR;
    int c = 0;
    #pragma unroll
    for (int j = 0; j < DNBR; ++j) {
        if (wts[j] > 0.f) {
            prow[c] = make_float2(wts[j], __int_as_float(nbs[j]));
            ++c;
        }
    }
    cnt_arr[node] = c;
}

// ---------------- Phase 3: sparse gather, lane = channel, ZERO shuffles ------
// Wave per 4 nodes. Per node: uniform cnt + guarded uniform pair-block loads,
// then up to cnt independent 2B/lane gathers (one 128B line each), FMA into
// per-lane acc, single coalesced 4B store. All guards wave-uniform.
__global__ __launch_bounds__(256) void out_kernel(
    const float2* __restrict__ alpha_c, const int* __restrict__ cnt_arr,
    const __hip_bfloat16* __restrict__ zb, float* __restrict__ out, int n)
{
    const int lane = threadIdx.x & 63;
    const int wv   = blockIdx.x * 4 + (threadIdx.x >> 6);
    const int base = wv * 4;
    if (base >= n) return;
    const unsigned short* zs = reinterpret_cast<const unsigned short*>(zb);

    #pragma unroll
    for (int i = 0; i < 4; ++i) {
        const int node = base + i;
        const int ni = (node < n) ? node : n - 1;
        const int cnt = cnt_arr[ni];
        const u32x4* pr = reinterpret_cast<const u32x4*>(alpha_c + (size_t)ni * DNBR);

        float acc = 0.f;
        union { unsigned u; float f; } w;

        // pairs are 8B; each u32x4 block holds 2 pairs -> 8 blocks cover 16
        #define PAIRBLK2(Q)                                                       \
        if (Q * 2 < cnt) {                                                        \
            const u32x4 p = pr[Q];                                                \
            {                                                                     \
                const float aw = __uint_as_float(p[0]);                           \
                const unsigned short zu = zs[(size_t)(int)p[1] * OUTDIM + lane];  \
                w.u = (unsigned)zu << 16;                                         \
                acc = fmaf(aw, w.f, acc);                                         \
            }                                                                     \
            if (Q * 2 + 1 < cnt) {                                                \
                const float aw = __uint_as_float(p[2]);                           \
                const unsigned short zu = zs[(size_t)(int)p[3] * OUTDIM + lane];  \
                w.u = (unsigned)zu << 16;                                         \
                acc = fmaf(aw, w.f, acc);                                         \
            }                                                                     \
        }
        PAIRBLK2(0) PAIRBLK2(1) PAIRBLK2(2) PAIRBLK2(3)
        PAIRBLK2(4) PAIRBLK2(5) PAIRBLK2(6) PAIRBLK2(7)
        #undef PAIRBLK2

        if (node < n)
            out[(size_t)node * OUTDIM + lane] = acc;
    }
}

extern "C" void kernel_launch(void* const* d_in, const int* in_sizes, int n_in,
                              void* d_out, int out_size, void* d_ws, size_t ws_size,
                              hipStream_t stream) {
    const float* h      = (const float*)d_in[0];
    const int*   nbr    = (const int*)  d_in[1];
    const float* wbias  = (const float*)d_in[2];
    const float* W_fc   = (const float*)d_in[3];
    const float* W_attn = (const float*)d_in[4];
    float* out = (float*)d_out;

    const int n = in_sizes[0] / INDIM;   // 100000

    // ws: zb (n*64 bf16) | s_src (n f32) | s_dst (n f32) | alpha_c (n*16 f2) | cnt (n i32)
    __hip_bfloat16* zb = (__hip_bfloat16*)d_ws;
    float* s_src = (float*)((char*)d_ws + (size_t)n * OUTDIM * sizeof(__hip_bfloat16));
    float* s_dst = s_src + n;
    float2* alpha_c = (float2*)(s_dst + n);
    int* cnt_arr = (int*)(alpha_c + (size_t)n * DNBR);

    fc_mfma<<<(n + 63) / 64, 256, 0, stream>>>(h, W_fc, W_attn, zb, s_src, s_dst, n);
    alpha_kernel<<<(n + 255) / 256, 256, 0, stream>>>(nbr, wbias, s_src, s_dst, alpha_c, cnt_arr, n);
    out_kernel<<<(n + 15) / 16, 256, 0, stream>>>(alpha_c, cnt_arr, zb, out, n);
}

// Round 15
// 49.806 us; speedup vs baseline: 1.7840x; 1.7840x over previous
//
#include <hip/hip_runtime.h>
#include <hip/hip_bf16.h>

#define DNBR   16
#define INDIM  128
#define OUTDIM 64

typedef __attribute__((ext_vector_type(8))) short bf16x8;
typedef __attribute__((ext_vector_type(4))) float f32x4;
typedef __attribute__((ext_vector_type(4))) unsigned u32x4;

union BF8 { bf16x8 v; u32x4 u; };

__device__ __forceinline__ unsigned cvt_pk_bf16(float lo, float hi) {
    unsigned r;
    asm("v_cvt_pk_bf16_f32 %0, %1, %2" : "=v"(r) : "v"(lo), "v"(hi));
    return r;
}

// ---------------- Phase 1: z = h @ W_fc^T via bf16 MFMA, + s_src/s_dst -------
__global__ __launch_bounds__(256) void fc_mfma(
    const float* __restrict__ h, const float* __restrict__ W_fc,
    const float* __restrict__ W_attn, __hip_bfloat16* __restrict__ zb,
    float* __restrict__ s_src, float* __restrict__ s_dst, int n)
{
    __shared__ unsigned wl[4096];   // 16 KB: slot(ct,kk,lane) -> 4 u32 (8 bf16)

    const int tid = threadIdx.x;
    #pragma unroll
    for (int s4 = 0; s4 < 4; ++s4) {
        const int slot = tid + 256 * s4;      // 0..1023
        const int lane_s = slot & 63;
        const int ckk  = slot >> 6;           // ct*4+kk
        const int ct_s = ckk >> 2, kk_s = ckk & 3;
        const int lm_s = lane_s & 15, lg_s = lane_s >> 4;
        const float* wr = W_fc + (size_t)(ct_s * 16 + lm_s) * INDIM + kk_s * 32 + lg_s * 8;
        const float4 w0 = *reinterpret_cast<const float4*>(wr);
        const float4 w1 = *reinterpret_cast<const float4*>(wr + 4);
        wl[slot * 4 + 0] = cvt_pk_bf16(w0.x, w0.y);
        wl[slot * 4 + 1] = cvt_pk_bf16(w0.z, w0.w);
        wl[slot * 4 + 2] = cvt_pk_bf16(w1.x, w1.y);
        wl[slot * 4 + 3] = cvt_pk_bf16(w1.z, w1.w);
    }
    __syncthreads();

    const int lane  = threadIdx.x & 63;
    const int wid   = threadIdx.x >> 6;
    const int node0 = blockIdx.x * 64 + wid * 16;
    if (node0 >= n) return;
    const int lm = lane & 15;
    const int lg = lane >> 4;

    bf16x8 bfrag[4][4];
    #pragma unroll
    for (int ct = 0; ct < 4; ++ct)
        #pragma unroll
        for (int kk = 0; kk < 4; ++kk) {
            BF8 u;
            u.u = *reinterpret_cast<const u32x4*>(&wl[(size_t)((ct * 4 + kk) * 64 + lane) * 4]);
            bfrag[ct][kk] = u.v;
        }

    const int arow = (node0 + lm < n) ? (node0 + lm) : (n - 1);
    const float* hr = h + (size_t)arow * INDIM;
    bf16x8 af[4];
    #pragma unroll
    for (int kk = 0; kk < 4; ++kk) {
        const float4 a0 = *reinterpret_cast<const float4*>(hr + kk * 32 + lg * 8);
        const float4 a1 = *reinterpret_cast<const float4*>(hr + kk * 32 + lg * 8 + 4);
        BF8 u;
        u.u[0] = cvt_pk_bf16(a0.x, a0.y);
        u.u[1] = cvt_pk_bf16(a0.z, a0.w);
        u.u[2] = cvt_pk_bf16(a1.x, a1.y);
        u.u[3] = cvt_pk_bf16(a1.z, a1.w);
        af[kk] = u.v;
    }

    f32x4 acc[4];
    #pragma unroll
    for (int ct = 0; ct < 4; ++ct) acc[ct] = (f32x4){0.f, 0.f, 0.f, 0.f};
    #pragma unroll
    for (int kk = 0; kk < 4; ++kk)
        #pragma unroll
        for (int ct = 0; ct < 4; ++ct)
            acc[ct] = __builtin_amdgcn_mfma_f32_16x16x32_bf16(af[kk], bfrag[ct][kk], acc[ct], 0, 0, 0);

    float ps[4] = {0.f, 0.f, 0.f, 0.f};
    float pd[4] = {0.f, 0.f, 0.f, 0.f};
    unsigned short* zbs = reinterpret_cast<unsigned short*>(zb);
    #pragma unroll
    for (int ct = 0; ct < 4; ++ct) {
        const float as = W_attn[ct * 16 + lm];
        const float ad = W_attn[OUTDIM + ct * 16 + lm];
        #pragma unroll
        for (int r = 0; r < 4; ++r) {
            const float v = acc[ct][r];                 // C[(lg*4+r)][ct*16+lm]
            const int grow = node0 + lg * 4 + r;
            if (grow < n)
                zbs[(size_t)grow * OUTDIM + ct * 16 + lm] =
                    (unsigned short)(cvt_pk_bf16(v, v) & 0xFFFFu);
            ps[r] = fmaf(v, as, ps[r]);
            pd[r] = fmaf(v, ad, pd[r]);
        }
    }
    #pragma unroll
    for (int off = 1; off < 16; off <<= 1) {
        #pragma unroll
        for (int r = 0; r < 4; ++r) {
            ps[r] += __shfl_xor(ps[r], off, 64);
            pd[r] += __shfl_xor(pd[r], off, 64);
        }
    }
    if (lm == 0) {
        #pragma unroll
        for (int r = 0; r < 4; ++r) {
            const int grow = node0 + lg * 4 + r;
            if (grow < n) { s_src[grow] = ps[r]; s_dst[grow] = pd[r]; }
        }
    }
}

// ---------------- Phase 2: fused entmax + sparse ILP gather ------------------
// Wave owns 4 nodes. Lane-parallel entmax (16-lane group/node) compacts
// nonzero (w, idx) pairs into per-wave LDS, zero-filled with (0, idx=0).
// Consume: lane = channel; per node 8 uniform ds_read_b128 (pair broadcast)
// + 16 UNGUARDED independent 2B gathers (zero slots hit L1-hot row 0)
// + 16 FMA + one coalesced store. No shuffles, no branches, full load ILP.
__global__ __launch_bounds__(256) void fused_out(
    const int* __restrict__ nbr, const float* __restrict__ wbias,
    const __hip_bfloat16* __restrict__ zb, const float* __restrict__ s_src,
    const float* __restrict__ s_dst, float* __restrict__ out, int n)
{
    __shared__ float2 pair_lds[4][4][DNBR];   // [wid][node][slot] = (w, idx-bits)

    const int lane = threadIdx.x & 63;
    const int wid  = threadIdx.x >> 6;
    const int wv   = blockIdx.x * 4 + wid;
    const int base = wv * 4;
    if (base >= n) return;

    // ---- entmax phase: group q = lane>>4 handles node base+q, slot j=lane&15
    {
        const int q = lane >> 4;
        const int j = lane & 15;
        const int gb = lane & 48;            // group base lane
        const int node_q = base + q;
        const int nq = (node_q < n) ? node_q : n - 1;

        const int   nbj = nbr  [(size_t)nq * DNBR + j];
        const float wj  = wbias[(size_t)nq * DNBR + j];
        const float sd  = s_dst[nq];
        float e = s_src[nbj] + sd;
        e = (e >= 0.f) ? e : 0.01f * e;
        float x = 0.5f * (e + wj);

        // group max, subtract
        float m = x;
        m = fmaxf(m, __shfl_xor(m, 1, 64));
        m = fmaxf(m, __shfl_xor(m, 2, 64));
        m = fmaxf(m, __shfl_xor(m, 4, 64));
        m = fmaxf(m, __shfl_xor(m, 8, 64));
        x -= m;

        // bitonic sort DESCENDING across the 16-lane group
        float v = x;
        #pragma unroll
        for (int k = 2; k <= 16; k <<= 1) {
            #pragma unroll
            for (int s = k >> 1; s >= 1; s >>= 1) {
                const float other = __shfl_xor(v, s, 64);
                const bool lower = ((j & s) == 0);
                const bool up    = ((j & k) == 0);
                v = (lower == up) ? fmaxf(v, other) : fminf(v, other);
            }
        }

        // inclusive scans of v and v^2 over ranks 0..j
        float cs = v, css = v * v;
        #pragma unroll
        for (int off = 1; off < 16; off <<= 1) {
            const int src = gb + ((j >= off) ? (j - off) : 0);
            const float t1 = __shfl(cs,  src, 64);
            const float t2 = __shfl(css, src, 64);
            if (j >= off) { cs += t1; css += t2; }
        }

        const float kkf    = (float)(j + 1);
        const float mean   = cs / kkf;
        const float meansq = css / kkf;
        const float ssv    = kkf * (meansq - mean * mean);
        const float delta  = (1.f - ssv) / kkf;
        const float sq     = (delta > 0.f) ? sqrtf(delta) : 0.f;
        const float tau    = mean - sq;

        const unsigned long long bal = __ballot(tau <= v);
        const int supp = (int)__popcll((bal >> gb) & 0xFFFFull);
        const float tau_star = __shfl(tau, gb + supp - 1, 64);

        const float y = fmaxf(x - tau_star, 0.f);
        const float y2 = y * y;

        // zero-fill, then compact nonzero pairs to the front (same-wave order)
        pair_lds[wid][q][j] = make_float2(0.f, __int_as_float(0));
        const unsigned long long nz = __ballot(y2 > 0.f);
        const unsigned grpmask = (unsigned)((nz >> gb) & 0xFFFFull);
        const int rank = __popc(grpmask & ((1u << j) - 1u));
        if (y2 > 0.f)
            pair_lds[wid][q][rank] = make_float2(y2, __int_as_float(nbj));
    }
    // same-wave LDS handoff (DS ops in program order within a wave)

    // ---- consume: lane = channel, branch-free, all 16 gathers independent
    const unsigned short* zs = reinterpret_cast<const unsigned short*>(zb);

    #pragma unroll
    for (int i = 0; i < 4; ++i) {
        const int node = base + i;

        // 8 uniform ds_read_b128: all 16 (w, idx) pairs
        float4 pq0 = *reinterpret_cast<const float4*>(&pair_lds[wid][i][0]);
        float4 pq1 = *reinterpret_cast<const float4*>(&pair_lds[wid][i][2]);
        float4 pq2 = *reinterpret_cast<const float4*>(&pair_lds[wid][i][4]);
        float4 pq3 = *reinterpret_cast<const float4*>(&pair_lds[wid][i][6]);
        float4 pq4 = *reinterpret_cast<const float4*>(&pair_lds[wid][i][8]);
        float4 pq5 = *reinterpret_cast<const float4*>(&pair_lds[wid][i][10]);
        float4 pq6 = *reinterpret_cast<const float4*>(&pair_lds[wid][i][12]);
        float4 pq7 = *reinterpret_cast<const float4*>(&pair_lds[wid][i][14]);

        float acc = 0.f;
        union { unsigned u; float f; } w;
        #define G2(pq)                                                              \
        {                                                                           \
            const unsigned short zu0 = zs[(size_t)__float_as_int((pq).y) * OUTDIM + lane]; \
            const unsigned short zu1 = zs[(size_t)__float_as_int((pq).w) * OUTDIM + lane]; \
            w.u = (unsigned)zu0 << 16; acc = fmaf((pq).x, w.f, acc);                \
            w.u = (unsigned)zu1 << 16; acc = fmaf((pq).z, w.f, acc);                \
        }
        G2(pq0) G2(pq1) G2(pq2) G2(pq3) G2(pq4) G2(pq5) G2(pq6) G2(pq7)
        #undef G2

        if (node < n)
            out[(size_t)node * OUTDIM + lane] = acc;
    }
}

extern "C" void kernel_launch(void* const* d_in, const int* in_sizes, int n_in,
                              void* d_out, int out_size, void* d_ws, size_t ws_size,
                              hipStream_t stream) {
    const float* h      = (const float*)d_in[0];
    const int*   nbr    = (const int*)  d_in[1];
    const float* wbias  = (const float*)d_in[2];
    const float* W_fc   = (const float*)d_in[3];
    const float* W_attn = (const float*)d_in[4];
    float* out = (float*)d_out;

    const int n = in_sizes[0] / INDIM;   // 100000

    // ws: zb (n*64 bf16) | s_src (n f32) | s_dst (n f32)
    __hip_bfloat16* zb = (__hip_bfloat16*)d_ws;
    float* s_src = (float*)((char*)d_ws + (size_t)n * OUTDIM * sizeof(__hip_bfloat16));
    float* s_dst = s_src + n;

    fc_mfma<<<(n + 63) / 64, 256, 0, stream>>>(h, W_fc, W_attn, zb, s_src, s_dst, n);
    fused_out<<<(n + 15) / 16, 256, 0, stream>>>(nbr, wbias, zb, s_src, s_dst, out, n);
}

// Round 16
// 45.852 us; speedup vs baseline: 1.9379x; 1.0862x over previous
//
#include <hip/hip_runtime.h>
#include <hip/hip_bf16.h>

#define DNBR   16
#define INDIM  128
#define OUTDIM 64

typedef __attribute__((ext_vector_type(8))) short bf16x8;
typedef __attribute__((ext_vector_type(4))) float f32x4;
typedef __attribute__((ext_vector_type(4))) unsigned u32x4;

union BF8 { bf16x8 v; u32x4 u; };

__device__ __forceinline__ unsigned cvt_pk_bf16(float lo, float hi) {
    unsigned r;
    asm("v_cvt_pk_bf16_f32 %0, %1, %2" : "=v"(r) : "v"(lo), "v"(hi));
    return r;
}

// ---------------- Phase 1: z = h @ W_fc^T via bf16 MFMA, + s_src/s_dst -------
__global__ __launch_bounds__(256) void fc_mfma(
    const float* __restrict__ h, const float* __restrict__ W_fc,
    const float* __restrict__ W_attn, __hip_bfloat16* __restrict__ zb,
    float* __restrict__ s_src, float* __restrict__ s_dst, int n)
{
    __shared__ unsigned wl[4096];   // 16 KB: slot(ct,kk,lane) -> 4 u32 (8 bf16)

    const int tid = threadIdx.x;
    #pragma unroll
    for (int s4 = 0; s4 < 4; ++s4) {
        const int slot = tid + 256 * s4;      // 0..1023
        const int lane_s = slot & 63;
        const int ckk  = slot >> 6;           // ct*4+kk
        const int ct_s = ckk >> 2, kk_s = ckk & 3;
        const int lm_s = lane_s & 15, lg_s = lane_s >> 4;
        const float* wr = W_fc + (size_t)(ct_s * 16 + lm_s) * INDIM + kk_s * 32 + lg_s * 8;
        const float4 w0 = *reinterpret_cast<const float4*>(wr);
        const float4 w1 = *reinterpret_cast<const float4*>(wr + 4);
        wl[slot * 4 + 0] = cvt_pk_bf16(w0.x, w0.y);
        wl[slot * 4 + 1] = cvt_pk_bf16(w0.z, w0.w);
        wl[slot * 4 + 2] = cvt_pk_bf16(w1.x, w1.y);
        wl[slot * 4 + 3] = cvt_pk_bf16(w1.z, w1.w);
    }
    __syncthreads();

    const int lane  = threadIdx.x & 63;
    const int wid   = threadIdx.x >> 6;
    const int node0 = blockIdx.x * 64 + wid * 16;
    if (node0 >= n) return;
    const int lm = lane & 15;
    const int lg = lane >> 4;

    bf16x8 bfrag[4][4];
    #pragma unroll
    for (int ct = 0; ct < 4; ++ct)
        #pragma unroll
        for (int kk = 0; kk < 4; ++kk) {
            BF8 u;
            u.u = *reinterpret_cast<const u32x4*>(&wl[(size_t)((ct * 4 + kk) * 64 + lane) * 4]);
            bfrag[ct][kk] = u.v;
        }

    const int arow = (node0 + lm < n) ? (node0 + lm) : (n - 1);
    const float* hr = h + (size_t)arow * INDIM;
    bf16x8 af[4];
    #pragma unroll
    for (int kk = 0; kk < 4; ++kk) {
        const float4 a0 = *reinterpret_cast<const float4*>(hr + kk * 32 + lg * 8);
        const float4 a1 = *reinterpret_cast<const float4*>(hr + kk * 32 + lg * 8 + 4);
        BF8 u;
        u.u[0] = cvt_pk_bf16(a0.x, a0.y);
        u.u[1] = cvt_pk_bf16(a0.z, a0.w);
        u.u[2] = cvt_pk_bf16(a1.x, a1.y);
        u.u[3] = cvt_pk_bf16(a1.z, a1.w);
        af[kk] = u.v;
    }

    f32x4 acc[4];
    #pragma unroll
    for (int ct = 0; ct < 4; ++ct) acc[ct] = (f32x4){0.f, 0.f, 0.f, 0.f};
    #pragma unroll
    for (int kk = 0; kk < 4; ++kk)
        #pragma unroll
        for (int ct = 0; ct < 4; ++ct)
            acc[ct] = __builtin_amdgcn_mfma_f32_16x16x32_bf16(af[kk], bfrag[ct][kk], acc[ct], 0, 0, 0);

    float ps[4] = {0.f, 0.f, 0.f, 0.f};
    float pd[4] = {0.f, 0.f, 0.f, 0.f};
    unsigned short* zbs = reinterpret_cast<unsigned short*>(zb);
    const bool full = (node0 + 16 <= n);   // wave-uniform fast path
    #pragma unroll
    for (int ct = 0; ct < 4; ++ct) {
        const float as = W_attn[ct * 16 + lm];
        const float ad = W_attn[OUTDIM + ct * 16 + lm];
        #pragma unroll
        for (int r = 0; r < 4; ++r) {
            const float v = acc[ct][r];                 // C[(lg*4+r)][ct*16+lm]
            const int grow = node0 + lg * 4 + r;
            if (full || grow < n)
                zbs[(size_t)grow * OUTDIM + ct * 16 + lm] =
                    (unsigned short)(cvt_pk_bf16(v, v) & 0xFFFFu);
            ps[r] = fmaf(v, as, ps[r]);
            pd[r] = fmaf(v, ad, pd[r]);
        }
    }
    #pragma unroll
    for (int off = 1; off < 16; off <<= 1) {
        #pragma unroll
        for (int r = 0; r < 4; ++r) {
            ps[r] += __shfl_xor(ps[r], off, 64);
            pd[r] += __shfl_xor(pd[r], off, 64);
        }
    }
    if (lm == 0) {
        #pragma unroll
        for (int r = 0; r < 4; ++r) {
            const int grow = node0 + lg * 4 + r;
            if (full || grow < n) { s_src[grow] = ps[r]; s_dst[grow] = pd[r]; }
        }
    }
}

// ---------------- tiered consume: NS slots, branch-free, full ILP ------------
template<int NS>
__device__ __forceinline__ void consume_nodes(
    const float2 (*pl)[DNBR], const unsigned short* zs,
    float* __restrict__ out, int base, int lane, int n)
{
    #pragma unroll
    for (int i = 0; i < 4; ++i) {
        const int node = base + i;
        float4 pq[NS / 2];
        #pragma unroll
        for (int q = 0; q < NS / 2; ++q)
            pq[q] = *reinterpret_cast<const float4*>(&pl[i][2 * q]);

        float acc = 0.f;
        union { unsigned u; float f; } w;
        #pragma unroll
        for (int q = 0; q < NS / 2; ++q) {
            const unsigned short zu0 = zs[(size_t)__float_as_int(pq[q].y) * OUTDIM + lane];
            const unsigned short zu1 = zs[(size_t)__float_as_int(pq[q].w) * OUTDIM + lane];
            w.u = (unsigned)zu0 << 16; acc = fmaf(pq[q].x, w.f, acc);
            w.u = (unsigned)zu1 << 16; acc = fmaf(pq[q].z, w.f, acc);
        }
        if (node < n)
            out[(size_t)node * OUTDIM + lane] = acc;
    }
}

// ---------------- Phase 2: fused entmax + sparse tiered gather ---------------
// Wave owns 4 nodes. Lane-parallel entmax (16-lane group/node) compacts
// nonzero (w, idx) pairs into per-wave LDS (zero-filled); per-node nonzero
// counts -> wave max -> UNIFORM branch into statically-unrolled 8/12/16-slot
// consume (no per-slot guards). Gathers are wave-uniform-idx coalesced lines.
__global__ __launch_bounds__(256) void fused_out(
    const int* __restrict__ nbr, const float* __restrict__ wbias,
    const __hip_bfloat16* __restrict__ zb, const float* __restrict__ s_src,
    const float* __restrict__ s_dst, float* __restrict__ out, int n)
{
    __shared__ float2 pair_lds[4][4][DNBR];   // [wid][node][slot] = (w, idx-bits)
    __shared__ int    cnt_lds[4][4];

    const int lane = threadIdx.x & 63;
    const int wid  = threadIdx.x >> 6;
    const int wv   = blockIdx.x * 4 + wid;
    const int base = wv * 4;
    if (base >= n) return;

    // ---- entmax phase: group q = lane>>4 handles node base+q, slot j=lane&15
    {
        const int q = lane >> 4;
        const int j = lane & 15;
        const int gb = lane & 48;            // group base lane
        const int node_q = base + q;
        const int nq = (node_q < n) ? node_q : n - 1;

        const int   nbj = nbr  [(size_t)nq * DNBR + j];
        const float wj  = wbias[(size_t)nq * DNBR + j];
        const float sd  = s_dst[nq];
        float e = s_src[nbj] + sd;
        e = (e >= 0.f) ? e : 0.01f * e;
        float x = 0.5f * (e + wj);

        // group max, subtract
        float m = x;
        m = fmaxf(m, __shfl_xor(m, 1, 64));
        m = fmaxf(m, __shfl_xor(m, 2, 64));
        m = fmaxf(m, __shfl_xor(m, 4, 64));
        m = fmaxf(m, __shfl_xor(m, 8, 64));
        x -= m;

        // bitonic sort DESCENDING across the 16-lane group
        float v = x;
        #pragma unroll
        for (int k = 2; k <= 16; k <<= 1) {
            #pragma unroll
            for (int s = k >> 1; s >= 1; s >>= 1) {
                const float other = __shfl_xor(v, s, 64);
                const bool lower = ((j & s) == 0);
                const bool up    = ((j & k) == 0);
                v = (lower == up) ? fmaxf(v, other) : fminf(v, other);
            }
        }

        // inclusive scans of v and v^2 over ranks 0..j
        float cs = v, css = v * v;
        #pragma unroll
        for (int off = 1; off < 16; off <<= 1) {
            const int src = gb + ((j >= off) ? (j - off) : 0);
            const float t1 = __shfl(cs,  src, 64);
            const float t2 = __shfl(css, src, 64);
            if (j >= off) { cs += t1; css += t2; }
        }

        const float kkf    = (float)(j + 1);
        const float mean   = cs / kkf;
        const float meansq = css / kkf;
        const float ssv    = kkf * (meansq - mean * mean);
        const float delta  = (1.f - ssv) / kkf;
        const float sq     = (delta > 0.f) ? sqrtf(delta) : 0.f;
        const float tau    = mean - sq;

        const unsigned long long bal = __ballot(tau <= v);
        const int supp = (int)__popcll((bal >> gb) & 0xFFFFull);
        const float tau_star = __shfl(tau, gb + supp - 1, 64);

        const float y = fmaxf(x - tau_star, 0.f);
        const float y2 = y * y;

        // zero-fill, then compact nonzero pairs to the front (same-wave order)
        pair_lds[wid][q][j] = make_float2(0.f, __int_as_float(0));
        const unsigned long long nz = __ballot(y2 > 0.f);
        const unsigned grpmask = (unsigned)((nz >> gb) & 0xFFFFull);
        const int rank = __popc(grpmask & ((1u << j) - 1u));
        if (y2 > 0.f)
            pair_lds[wid][q][rank] = make_float2(y2, __int_as_float(nbj));
        if (j == 0) cnt_lds[wid][q] = __popc(grpmask);
    }
    // same-wave LDS handoff (DS ops in program order within a wave)

    const unsigned short* zs = reinterpret_cast<const unsigned short*>(zb);
    const int maxc = max(max(cnt_lds[wid][0], cnt_lds[wid][1]),
                         max(cnt_lds[wid][2], cnt_lds[wid][3]));   // wave-uniform

    if (maxc <= 8)
        consume_nodes<8>(pair_lds[wid], zs, out, base, lane, n);
    else if (maxc <= 12)
        consume_nodes<12>(pair_lds[wid], zs, out, base, lane, n);
    else
        consume_nodes<16>(pair_lds[wid], zs, out, base, lane, n);
}

extern "C" void kernel_launch(void* const* d_in, const int* in_sizes, int n_in,
                              void* d_out, int out_size, void* d_ws, size_t ws_size,
                              hipStream_t stream) {
    const float* h      = (const float*)d_in[0];
    const int*   nbr    = (const int*)  d_in[1];
    const float* wbias  = (const float*)d_in[2];
    const float* W_fc   = (const float*)d_in[3];
    const float* W_attn = (const float*)d_in[4];
    float* out = (float*)d_out;

    const int n = in_sizes[0] / INDIM;   // 100000

    // ws: zb (n*64 bf16) | s_src (n f32) | s_dst (n f32)
    __hip_bfloat16* zb = (__hip_bfloat16*)d_ws;
    float* s_src = (float*)((char*)d_ws + (size_t)n * OUTDIM * sizeof(__hip_bfloat16));
    float* s_dst = s_src + n;

    fc_mfma<<<(n + 63) / 64, 256, 0, stream>>>(h, W_fc, W_attn, zb, s_src, s_dst, n);
    fused_out<<<(n + 15) / 16, 256, 0, stream>>>(nbr, wbias, zb, s_src, s_dst, out, n);
}

// Round 17
// 45.366 us; speedup vs baseline: 1.9586x; 1.0107x over previous
//
#include <hip/hip_runtime.h>
#include <hip/hip_bf16.h>

#define DNBR   16
#define INDIM  128
#define OUTDIM 64

typedef __attribute__((ext_vector_type(8))) short bf16x8;
typedef __attribute__((ext_vector_type(4))) float f32x4;
typedef __attribute__((ext_vector_type(4))) unsigned u32x4;

union BF8 { bf16x8 v; u32x4 u; };

__device__ __forceinline__ unsigned cvt_pk_bf16(float lo, float hi) {
    unsigned r;
    asm("v_cvt_pk_bf16_f32 %0, %1, %2" : "=v"(r) : "v"(lo), "v"(hi));
    return r;
}

// ---------------- Phase 1: z = h @ W_fc^T via bf16 MFMA, + s_src/s_dst -------
__global__ __launch_bounds__(256) void fc_mfma(
    const float* __restrict__ h, const float* __restrict__ W_fc,
    const float* __restrict__ W_attn, __hip_bfloat16* __restrict__ zb,
    float* __restrict__ s_src, float* __restrict__ s_dst, int n)
{
    __shared__ unsigned wl[4096];   // 16 KB: slot(ct,kk,lane) -> 4 u32 (8 bf16)

    const int tid = threadIdx.x;
    #pragma unroll
    for (int s4 = 0; s4 < 4; ++s4) {
        const int slot = tid + 256 * s4;      // 0..1023
        const int lane_s = slot & 63;
        const int ckk  = slot >> 6;           // ct*4+kk
        const int ct_s = ckk >> 2, kk_s = ckk & 3;
        const int lm_s = lane_s & 15, lg_s = lane_s >> 4;
        const float* wr = W_fc + (size_t)(ct_s * 16 + lm_s) * INDIM + kk_s * 32 + lg_s * 8;
        const float4 w0 = *reinterpret_cast<const float4*>(wr);
        const float4 w1 = *reinterpret_cast<const float4*>(wr + 4);
        u32x4 o;
        o[0] = cvt_pk_bf16(w0.x, w0.y);
        o[1] = cvt_pk_bf16(w0.z, w0.w);
        o[2] = cvt_pk_bf16(w1.x, w1.y);
        o[3] = cvt_pk_bf16(w1.z, w1.w);
        *reinterpret_cast<u32x4*>(&wl[slot * 4]) = o;
    }
    __syncthreads();

    const int lane  = threadIdx.x & 63;
    const int wid   = threadIdx.x >> 6;
    const int node0 = blockIdx.x * 64 + wid * 16;
    if (node0 >= n) return;
    const int lm = lane & 15;
    const int lg = lane >> 4;

    bf16x8 bfrag[4][4];
    #pragma unroll
    for (int ct = 0; ct < 4; ++ct)
        #pragma unroll
        for (int kk = 0; kk < 4; ++kk) {
            BF8 u;
            u.u = *reinterpret_cast<const u32x4*>(&wl[(size_t)((ct * 4 + kk) * 64 + lane) * 4]);
            bfrag[ct][kk] = u.v;
        }

    const int arow = (node0 + lm < n) ? (node0 + lm) : (n - 1);
    const float* hr = h + (size_t)arow * INDIM;
    bf16x8 af[4];
    #pragma unroll
    for (int kk = 0; kk < 4; ++kk) {
        const float4 a0 = *reinterpret_cast<const float4*>(hr + kk * 32 + lg * 8);
        const float4 a1 = *reinterpret_cast<const float4*>(hr + kk * 32 + lg * 8 + 4);
        BF8 u;
        u.u[0] = cvt_pk_bf16(a0.x, a0.y);
        u.u[1] = cvt_pk_bf16(a0.z, a0.w);
        u.u[2] = cvt_pk_bf16(a1.x, a1.y);
        u.u[3] = cvt_pk_bf16(a1.z, a1.w);
        af[kk] = u.v;
    }

    f32x4 acc[4];
    #pragma unroll
    for (int ct = 0; ct < 4; ++ct) acc[ct] = (f32x4){0.f, 0.f, 0.f, 0.f};
    #pragma unroll
    for (int kk = 0; kk < 4; ++kk)
        #pragma unroll
        for (int ct = 0; ct < 4; ++ct)
            acc[ct] = __builtin_amdgcn_mfma_f32_16x16x32_bf16(af[kk], bfrag[ct][kk], acc[ct], 0, 0, 0);

    float ps[4] = {0.f, 0.f, 0.f, 0.f};
    float pd[4] = {0.f, 0.f, 0.f, 0.f};
    unsigned short* zbs = reinterpret_cast<unsigned short*>(zb);
    const bool full = (node0 + 16 <= n);   // wave-uniform fast path
    #pragma unroll
    for (int ct = 0; ct < 4; ++ct) {
        const float as = W_attn[ct * 16 + lm];
        const float ad = W_attn[OUTDIM + ct * 16 + lm];
        #pragma unroll
        for (int r = 0; r < 4; ++r) {
            const float v = acc[ct][r];                 // C[(lg*4+r)][ct*16+lm]
            const int grow = node0 + lg * 4 + r;
            if (full || grow < n)
                zbs[(size_t)grow * OUTDIM + ct * 16 + lm] =
                    (unsigned short)(cvt_pk_bf16(v, v) & 0xFFFFu);
            ps[r] = fmaf(v, as, ps[r]);
            pd[r] = fmaf(v, ad, pd[r]);
        }
    }
    #pragma unroll
    for (int off = 1; off < 16; off <<= 1) {
        #pragma unroll
        for (int r = 0; r < 4; ++r) {
            ps[r] += __shfl_xor(ps[r], off, 64);
            pd[r] += __shfl_xor(pd[r], off, 64);
        }
    }
    if (lm == 0) {
        #pragma unroll
        for (int r = 0; r < 4; ++r) {
            const int grow = node0 + lg * 4 + r;
            if (full || grow < n) { s_src[grow] = ps[r]; s_dst[grow] = pd[r]; }
        }
    }
}

// ---------------- tiered consume: NS slots, branch-free, full ILP ------------
template<int NS>
__device__ __forceinline__ void consume_nodes(
    const float2 (*pl)[DNBR], const unsigned short* zs,
    float* __restrict__ out, int base, int lane, int n)
{
    #pragma unroll
    for (int i = 0; i < 4; ++i) {
        const int node = base + i;
        float4 pq[(NS + 1) / 2];
        #pragma unroll
        for (int q = 0; q < (NS + 1) / 2; ++q)
            pq[q] = *reinterpret_cast<const float4*>(&pl[i][2 * q]);

        float acc = 0.f;
        union { unsigned u; float f; } w;
        #pragma unroll
        for (int q = 0; q < (NS + 1) / 2; ++q) {
            const unsigned short zu0 = zs[(size_t)__float_as_int(pq[q].y) * OUTDIM + lane];
            const unsigned short zu1 = zs[(size_t)__float_as_int(pq[q].w) * OUTDIM + lane];
            w.u = (unsigned)zu0 << 16; acc = fmaf(pq[q].x, w.f, acc);
            w.u = (unsigned)zu1 << 16; acc = fmaf(pq[q].z, w.f, acc);
        }
        if (node < n)
            out[(size_t)node * OUTDIM + lane] = acc;
    }
}

// ---------------- Phase 2: fused entmax + sparse tiered gather ---------------
// Wave owns 4 nodes. Lane-parallel entmax (16-lane group/node) compacts
// nonzero (w, idx) pairs into per-wave LDS (zero-filled); per-node nonzero
// counts -> wave max -> UNIFORM branch into statically-unrolled straight-line
// consume tiers {6,8,10,12,16} (no per-slot guards -> compiler batches loads).
__global__ __launch_bounds__(256) void fused_out(
    const int* __restrict__ nbr, const float* __restrict__ wbias,
    const __hip_bfloat16* __restrict__ zb, const float* __restrict__ s_src,
    const float* __restrict__ s_dst, float* __restrict__ out, int n)
{
    __shared__ float2 pair_lds[4][4][DNBR];   // [wid][node][slot] = (w, idx-bits)
    __shared__ int    cnt_lds[4][4];

    const int lane = threadIdx.x & 63;
    const int wid  = threadIdx.x >> 6;
    const int wv   = blockIdx.x * 4 + wid;
    const int base = wv * 4;
    if (base >= n) return;

    // ---- entmax phase: group q = lane>>4 handles node base+q, slot j=lane&15
    {
        const int q = lane >> 4;
        const int j = lane & 15;
        const int gb = lane & 48;            // group base lane
        const int node_q = base + q;
        const int nq = (node_q < n) ? node_q : n - 1;

        const int   nbj = nbr  [(size_t)nq * DNBR + j];
        const float wj  = wbias[(size_t)nq * DNBR + j];
        const float sd  = s_dst[nq];
        float e = s_src[nbj] + sd;
        e = (e >= 0.f) ? e : 0.01f * e;
        float x = 0.5f * (e + wj);

        // group max, subtract
        float m = x;
        m = fmaxf(m, __shfl_xor(m, 1, 64));
        m = fmaxf(m, __shfl_xor(m, 2, 64));
        m = fmaxf(m, __shfl_xor(m, 4, 64));
        m = fmaxf(m, __shfl_xor(m, 8, 64));
        x -= m;

        // bitonic sort DESCENDING across the 16-lane group
        float v = x;
        #pragma unroll
        for (int k = 2; k <= 16; k <<= 1) {
            #pragma unroll
            for (int s = k >> 1; s >= 1; s >>= 1) {
                const float other = __shfl_xor(v, s, 64);
                const bool lower = ((j & s) == 0);
                const bool up    = ((j & k) == 0);
                v = (lower == up) ? fmaxf(v, other) : fminf(v, other);
            }
        }

        // inclusive scans of v and v^2 over ranks 0..j
        float cs = v, css = v * v;
        #pragma unroll
        for (int off = 1; off < 16; off <<= 1) {
            const int src = gb + ((j >= off) ? (j - off) : 0);
            const float t1 = __shfl(cs,  src, 64);
            const float t2 = __shfl(css, src, 64);
            if (j >= off) { cs += t1; css += t2; }
        }

        const float kkf    = (float)(j + 1);
        const float mean   = cs / kkf;
        const float meansq = css / kkf;
        const float ssv    = kkf * (meansq - mean * mean);
        const float delta  = (1.f - ssv) / kkf;
        const float sq     = (delta > 0.f) ? sqrtf(delta) : 0.f;
        const float tau    = mean - sq;

        const unsigned long long bal = __ballot(tau <= v);
        const int supp = (int)__popcll((bal >> gb) & 0xFFFFull);
        const float tau_star = __shfl(tau, gb + supp - 1, 64);

        const float y = fmaxf(x - tau_star, 0.f);
        const float y2 = y * y;

        // zero-fill, then compact nonzero pairs to the front (same-wave order)
        pair_lds[wid][q][j] = make_float2(0.f, __int_as_float(0));
        const unsigned long long nz = __ballot(y2 > 0.f);
        const unsigned grpmask = (unsigned)((nz >> gb) & 0xFFFFull);
        const int rank = __popc(grpmask & ((1u << j) - 1u));
        if (y2 > 0.f)
            pair_lds[wid][q][rank] = make_float2(y2, __int_as_float(nbj));
        if (j == 0) cnt_lds[wid][q] = __popc(grpmask);
    }
    // same-wave LDS handoff (DS ops in program order within a wave)

    const unsigned short* zs = reinterpret_cast<const unsigned short*>(zb);
    const int maxc = max(max(cnt_lds[wid][0], cnt_lds[wid][1]),
                         max(cnt_lds[wid][2], cnt_lds[wid][3]));   // wave-uniform

    if (maxc <= 6)
        consume_nodes<6>(pair_lds[wid], zs, out, base, lane, n);
    else if (maxc <= 8)
        consume_nodes<8>(pair_lds[wid], zs, out, base, lane, n);
    else if (maxc <= 10)
        consume_nodes<10>(pair_lds[wid], zs, out, base, lane, n);
    else if (maxc <= 12)
        consume_nodes<12>(pair_lds[wid], zs, out, base, lane, n);
    else
        consume_nodes<16>(pair_lds[wid], zs, out, base, lane, n);
}

extern "C" void kernel_launch(void* const* d_in, const int* in_sizes, int n_in,
                              void* d_out, int out_size, void* d_ws, size_t ws_size,
                              hipStream_t stream) {
    const float* h      = (const float*)d_in[0];
    const int*   nbr    = (const int*)  d_in[1];
    const float* wbias  = (const float*)d_in[2];
    const float* W_fc   = (const float*)d_in[3];
    const float* W_attn = (const float*)d_in[4];
    float* out = (float*)d_out;

    const int n = in_sizes[0] / INDIM;   // 100000

    // ws: zb (n*64 bf16) | s_src (n f32) | s_dst (n f32)
    __hip_bfloat16* zb = (__hip_bfloat16*)d_ws;
    float* s_src = (float*)((char*)d_ws + (size_t)n * OUTDIM * sizeof(__hip_bfloat16));
    float* s_dst = s_src + n;

    fc_mfma<<<(n + 63) / 64, 256, 0, stream>>>(h, W_fc, W_attn, zb, s_src, s_dst, n);
    fused_out<<<(n + 15) / 16, 256, 0, stream>>>(nbr, wbias, zb, s_src, s_dst, out, n);
}